// Round 5
// baseline (207.722 us; speedup 1.0000x reference)
//
#include <hip/hip_runtime.h>
#include <stdint.h>

#define BATCH 128
#define PRI   8732
#define NCLS  21
#define NPR   3
#define TOTAL (BATCH * PRI)            // 1,117,696 (divisible by 256)
#define NBLK  (TOTAL / 256)            // 4366 blocks
#define NPART (TOTAL / 64)             // 17464 per-wave partial slots

// ws layout (no memset needed - every slot written unconditionally):
//   [0, KB)         uint32 keys[TOTAL]   monotone-mapped bg_loss; 0 for positives
//   [KB, +69856)    float pm[NPART]      per-wave mask-sum partials
//   [.., +69856)    float pp[NPART]      per-wave pos-loss partials
//   [.., +69856)    float pr[NPART]      per-wave reg-loss partials
//   [.., +1024)     double neg[BATCH]    per-row hard-negative loss sums

typedef const __attribute__((address_space(1))) void gv_t;
typedef __attribute__((address_space(3))) void lv_t;

// ---------------------------------------------------------------------------
// k_main: waves are FULLY INDEPENDENT (no __syncthreads). Each wave async-
// stages its own 64 anchors x 21 floats (5376 B) into its private LDS slice
// via global_load_lds (width 16), waits vmcnt(0) only (wave-coherent), then
// computes. 28 self-paced waves/CU keep loads in flight continuously
// (Little's law duty fix vs the barrier-coupled R4 structure).
// ---------------------------------------------------------------------------
__global__ __launch_bounds__(256)
void k_main(const float* __restrict__ conf, const float* __restrict__ pred,
            const int* __restrict__ labels, const float* __restrict__ gt,
            const float* __restrict__ mask, uint32_t* __restrict__ keys,
            float* __restrict__ pm, float* __restrict__ pp, float* __restrict__ pr)
{
  __shared__ __align__(16) float sconf[256 * NCLS];   // 21504 B -> 7 blocks/CU (28 waves)
  const int tid = threadIdx.x;
  const int wv  = tid >> 6;                           // wave id in block
  const int ln  = tid & 63;
  const long long wbase = ((long long)blockIdx.x * 4 + wv) * 64;   // this wave's anchor base

  // Wave-private slice: anchors [wbase, wbase+64) x 21 floats = 1344 floats = 336 float4.
  // wbase*21*4 = wbase/64 * 5376 bytes -> 16B-aligned.
  const float4* src4  = (const float4*)(conf + wbase * NCLS);
  float*        slice = sconf + wv * (64 * NCLS);

  #pragma unroll
  for (int i = 0; i < 5; ++i) {
    __builtin_amdgcn_global_load_lds(
        (gv_t*)(src4 + i * 64 + ln),
        (lv_t*)((float4*)slice + i * 64),
        16, 0, 0);
  }
  if (ln < 16) {                                      // tail: float4 slots 320..335
    __builtin_amdgcn_global_load_lds(
        (gv_t*)(src4 + 320 + ln),
        (lv_t*)((float4*)slice + 320),
        16, 0, 0);
  }

  // Independent register loads fly alongside the LDS staging.
  const long long a = wbase + ln;
  const int   lab = labels[a];
  const float mk  = mask[a];

  // Wave-coherent drain of the global_load_lds queue; no block barrier.
  asm volatile("s_waitcnt vmcnt(0)" ::: "memory");

  const float* cv = &slice[ln * NCLS];    // stride 21: gcd(21,32)=1 -> <=2-way alias (free)
  float m = cv[0];
  #pragma unroll
  for (int c = 1; c < NCLS; ++c) m = fmaxf(m, cv[c]);
  float s = 0.f;
  #pragma unroll
  for (int c = 0; c < NCLS; ++c) s += __expf(cv[c] - m);
  const float lse = m + __logf(s);
  const float bg  = lse - cv[0];          // >= 0 always (lse >= max >= cv[0])
  const bool  pos = lab > 0;

  float accm = mk, accp = 0.f, accr = 0.f;
  if (pos) {
    accp = mk * (lse - cv[lab]);
    const float4 pd = ((const float4*)pred)[a];
    const float4 g  = ((const float4*)gt)[a];
    float sl = 0.f, d, ad;
    d = pd.x - g.x; ad = fabsf(d); sl += (ad < 1.f) ? 0.5f * d * d : ad - 0.5f;
    d = pd.y - g.y; ad = fabsf(d); sl += (ad < 1.f) ? 0.5f * d * d : ad - 0.5f;
    d = pd.z - g.z; ad = fabsf(d); sl += (ad < 1.f) ? 0.5f * d * d : ad - 0.5f;
    d = pd.w - g.w; ad = fabsf(d); sl += (ad < 1.f) ? 0.5f * d * d : ad - 0.5f;
    accr = mk * sl;
  }
  keys[a] = pos ? 0u : (__float_as_uint(bg) | 0x80000000u);  // monotone map; pos -> 0 (-inf)

  // Per-wave reduction only; partials to ws (no barrier, no atomics).
  #pragma unroll
  for (int o = 32; o > 0; o >>= 1) {
    accm += __shfl_down(accm, o);
    accp += __shfl_down(accp, o);
    accr += __shfl_down(accr, o);
  }
  if (ln == 0) {
    const int gw = blockIdx.x * 4 + wv;
    pm[gw] = accm; pp[gw] = accp; pr[gw] = accr;
  }
}

// ---------------------------------------------------------------------------
// k_select: one block (512 threads) per batch row, keys register-resident.
// Exact k-th-largest key via MSB-first search, 2 bits per round (3 candidate
// thresholds, counts monotone) -> 16 barriers. Tie-exact top-k sum.
// ---------------------------------------------------------------------------
#define SEL_T 512
#define RPT   18                               // 8732 = 512*17 + 28

__global__ __launch_bounds__(SEL_T)
void k_select(const uint32_t* __restrict__ keys, double* __restrict__ neg)
{
  __shared__ int    slots[16 * 24 + 8];        // fresh region per round
  __shared__ int    ired[8];
  __shared__ double dred[8];
  const int tid  = threadIdx.x;
  const int w    = tid >> 6;
  const int lane = tid & 63;
  const uint32_t* row = keys + (size_t)blockIdx.x * PRI;

  uint32_t kr[RPT];
  #pragma unroll
  for (int r = 0; r < 17; ++r) kr[r] = row[tid + 512 * r];
  kr[17] = (tid < 28) ? row[tid + 8704] : 0u;  // pad 0: never >= any test (tests >= 2^31)

  // np = zero-key count (pad zeros excluded by tid<28 guard).
  int zc = 0;
  #pragma unroll
  for (int r = 0; r < 17; ++r) zc += (kr[r] == 0u) ? 1 : 0;
  if (tid < 28) zc += (kr[17] == 0u) ? 1 : 0;
  #pragma unroll
  for (int o = 32; o > 0; o >>= 1) zc += __shfl_down(zc, o);
  if (lane == 0) ired[w] = zc;
  __syncthreads();
  int np = 0;
  #pragma unroll
  for (int i = 0; i < 8; ++i) np += ired[i];   // uniform

  int k = np * NPR;
  const int nneg = PRI - np;
  if (k > nneg) k = nneg;

  double result = 0.0;
  if (k > 0) {                                 // uniform branch
    uint32_t cur = 0x80000000u;                // bit31 provably set: nneg >= k
    #pragma unroll 1
    for (int bit = 30; bit >= 1; bit -= 2) {
      const int rnd = (30 - bit) >> 1;
      const uint32_t tA = cur | (3u << (bit - 1));  // bits 11
      const uint32_t tB = cur | (1u << bit);        // bits 10
      const uint32_t tC = cur | (1u << (bit - 1));  // bits 01
      int cA = 0, cB = 0, cC = 0;
      #pragma unroll
      for (int r = 0; r < RPT; ++r) {
        cA += (int)__popcll(__ballot(kr[r] >= tA));
        cB += (int)__popcll(__ballot(kr[r] >= tB));
        cC += (int)__popcll(__ballot(kr[r] >= tC));
      }
      if (lane == 0) {
        int* sl = &slots[rnd * 24];
        sl[w] = cA; sl[8 + w] = cB; sl[16 + w] = cC;
      }
      __syncthreads();
      int TA = 0, TB = 0, TC = 0;
      const int* sl = &slots[rnd * 24];
      #pragma unroll
      for (int i = 0; i < 8; ++i) { TA += sl[i]; TB += sl[8 + i]; TC += sl[16 + i]; }
      cur = (TA >= k) ? tA : (TB >= k) ? tB : (TC >= k) ? tC : cur;  // largest v: count(>=v)>=k
    }
    {                                          // final bit 0
      const uint32_t t = cur | 1u;
      int c = 0;
      #pragma unroll
      for (int r = 0; r < RPT; ++r) c += (int)__popcll(__ballot(kr[r] >= t));
      if (lane == 0) slots[16 * 24 + w] = c;
      __syncthreads();
      int tot = 0;
      #pragma unroll
      for (int i = 0; i < 8; ++i) tot += slots[16 * 24 + i];
      if (tot >= k) cur = t;                   // cur == exact k-th largest key
    }

    const float thr = __uint_as_float(cur & 0x7fffffffu);
    double ssum = 0.0;
    int g = 0;
    #pragma unroll
    for (int r = 0; r < RPT; ++r) {
      if (kr[r] > cur) { ssum += (double)__uint_as_float(kr[r] & 0x7fffffffu); ++g; }
    }
    #pragma unroll
    for (int o = 32; o > 0; o >>= 1) { ssum += __shfl_down(ssum, o); g += __shfl_down(g, o); }
    if (lane == 0) { dred[w] = ssum; ired[w] = g; }
    __syncthreads();
    if (tid == 0) {
      double tot = 0.0; int gg = 0;
      #pragma unroll
      for (int i = 0; i < 8; ++i) { tot += dred[i]; gg += ired[i]; }
      result = tot + (double)(k - gg) * (double)thr;  // tied copies at threshold
    }
  }
  if (tid == 0) neg[blockIdx.x] = result;      // unconditional: ws is poisoned
}

// ---------------------------------------------------------------------------
// k_final: reduce per-wave partials (double accumulation) + write outputs.
// ---------------------------------------------------------------------------
__global__ __launch_bounds__(256)
void k_final(const float* __restrict__ pm, const float* __restrict__ pp,
             const float* __restrict__ pr, const double* __restrict__ neg,
             float* __restrict__ out)
{
  __shared__ double red[4][4];
  const int tid = threadIdx.x, w = tid >> 6, lane = tid & 63;
  double sm = 0.0, sp = 0.0, sr = 0.0, sn = 0.0;
  for (int i = tid; i < NPART; i += 256) {
    sm += (double)pm[i]; sp += (double)pp[i]; sr += (double)pr[i];
  }
  if (tid < BATCH) sn = neg[tid];
  #pragma unroll
  for (int o = 32; o > 0; o >>= 1) {
    sm += __shfl_down(sm, o); sp += __shfl_down(sp, o);
    sr += __shfl_down(sr, o); sn += __shfl_down(sn, o);
  }
  if (lane == 0) { red[0][w] = sm; red[1][w] = sp; red[2][w] = sr; red[3][w] = sn; }
  __syncthreads();
  if (tid == 0) {
    double m = 0, p = 0, r = 0, n = 0;
    #pragma unroll
    for (int i = 0; i < 4; ++i) { m += red[0][i]; p += red[1][i]; r += red[2][i]; n += red[3][i]; }
    out[0] = (float)(r / m);                   // regression_loss / all_batch_pos
    out[1] = (float)((p + n) / m);             // confidence_loss / all_batch_pos
  }
}

extern "C" void kernel_launch(void* const* d_in, const int* in_sizes, int n_in,
                              void* d_out, int out_size, void* d_ws, size_t ws_size,
                              hipStream_t stream) {
  const float* conf   = (const float*)d_in[0];
  const float* pred   = (const float*)d_in[1];
  const int*   labels = (const int*)d_in[2];
  const float* gt     = (const float*)d_in[3];
  const float* mask   = (const float*)d_in[4];
  float* out = (float*)d_out;

  char* ws = (char*)d_ws;
  const size_t keys_bytes = (size_t)TOTAL * sizeof(uint32_t);  // 4,470,784 (8-aligned)
  uint32_t* keys = (uint32_t*)ws;
  float*  pm  = (float*)(ws + keys_bytes);
  float*  pp  = pm + NPART;
  float*  pr  = pp + NPART;
  double* neg = (double*)(ws + keys_bytes + (size_t)3 * NPART * sizeof(float)); // 8-aligned

  k_main<<<NBLK, 256, 0, stream>>>(conf, pred, labels, gt, mask, keys, pm, pp, pr);
  k_select<<<BATCH, SEL_T, 0, stream>>>(keys, neg);
  k_final<<<1, 256, 0, stream>>>(pm, pp, pr, neg, out);
}

// Round 6
// 204.281 us; speedup vs baseline: 1.0168x; 1.0168x over previous
//
#include <hip/hip_runtime.h>
#include <stdint.h>

#define BATCH  128
#define PRI    8732
#define NCLS   21
#define NPR    3
#define TOTAL  (BATCH * PRI)           // 1,117,696 = 4366 chunks of 256
#define NCHUNK (TOTAL / 256)           // 4366
#define CPBLK  4                       // chunks per block
#define GBLK   1092                    // ceil(4366/4); block 1091 does 2 chunks
#define NPART  (GBLK * 4)              // 4368 per-wave partial slots

// ws layout (no memset needed - every slot written unconditionally):
//   [0, KB)        uint32 keys[TOTAL]  monotone-mapped bg_loss; 0 for positives
//   [KB, +17472)   float pm[NPART]     per-wave mask-sum partials
//   [.., +17472)   float pp[NPART]     per-wave pos-loss partials
//   [.., +17472)   float pr[NPART]     per-wave reg-loss partials
//   [.., +1024)    double neg[BATCH]   per-row hard-negative loss sums

// 4-byte-aligned float4: per-lane conf rows start at a*84 B (dword-aligned only).
// gfx950 supports dword-aligned dwordx4 global loads (unaligned-access-mode).
typedef float f4a4 __attribute__((ext_vector_type(4), aligned(4)));

struct Pf {                            // one anchor's prefetched state (all registers)
  f4a4  q0, q1, q2, q3, q4;            // conf[0..19]
  float t;                             // conf[20]
  int   lab;
  float mk;
  float4 pd, g;                        // pred/gt rows (16B aligned)
};

__device__ __forceinline__ void issue(Pf& p, const float* __restrict__ conf,
                                      const float* __restrict__ pred,
                                      const float* __restrict__ gt,
                                      const int* __restrict__ labels,
                                      const float* __restrict__ mask, long long a) {
  const float* ap = conf + a * NCLS;
  p.q0 = *(const f4a4*)(ap);
  p.q1 = *(const f4a4*)(ap + 4);
  p.q2 = *(const f4a4*)(ap + 8);
  p.q3 = *(const f4a4*)(ap + 12);
  p.q4 = *(const f4a4*)(ap + 16);
  p.t  = ap[20];
  p.lab = labels[a];
  p.mk  = mask[a];
  p.pd  = ((const float4*)pred)[a];
  p.g   = ((const float4*)gt)[a];
}

// ---------------------------------------------------------------------------
// k_main: no LDS, no barriers. 1092 long-lived blocks x 4 chunks, depth-1
// register prefetch: chunk n+1's 10 loads fly while chunk n's softmax runs.
// All waves fully independent; per-wave partials to ws.
// ---------------------------------------------------------------------------
__global__ __launch_bounds__(256)
void k_main(const float* __restrict__ conf, const float* __restrict__ pred,
            const int* __restrict__ labels, const float* __restrict__ gt,
            const float* __restrict__ mask, uint32_t* __restrict__ keys,
            float* __restrict__ pm, float* __restrict__ pp, float* __restrict__ pr)
{
  const int tid = threadIdx.x;
  const int b   = blockIdx.x;
  int nch = NCHUNK - b * CPBLK;
  if (nch <= 0) return;                        // (GBLK*CPBLK == 4368: only tail trim)
  if (nch > CPBLK) nch = CPBLK;

  long long ca = (long long)b * (CPBLK * 256) + tid;   // this thread's current anchor

  Pf pf;
  issue(pf, conf, pred, gt, labels, mask, ca);

  float accm = 0.f, accp = 0.f, accr = 0.f;

  #pragma unroll 1
  for (int it = 0; it < nch; ++it) {
    Pf cur = pf;                               // waits only for pf's own loads
    const long long a = ca;
    if (it + 1 < nch) {                        // block-uniform branch
      ca += 256;
      issue(pf, conf, pred, gt, labels, mask, ca);   // in flight across compute below
    }

    float c[21] = { cur.q0.x, cur.q0.y, cur.q0.z, cur.q0.w,
                    cur.q1.x, cur.q1.y, cur.q1.z, cur.q1.w,
                    cur.q2.x, cur.q2.y, cur.q2.z, cur.q2.w,
                    cur.q3.x, cur.q3.y, cur.q3.z, cur.q3.w,
                    cur.q4.x, cur.q4.y, cur.q4.z, cur.q4.w, cur.t };
    float m = c[0];
    #pragma unroll
    for (int i = 1; i < NCLS; ++i) m = fmaxf(m, c[i]);
    float s = 0.f, sel = c[0];
    #pragma unroll
    for (int i = 0; i < NCLS; ++i) {
      s += __expf(c[i] - m);
      if (i > 0) sel = (cur.lab == i) ? c[i] : sel;   // cndmask, no dynamic indexing
    }
    const float lse = m + __logf(s);
    const float bg  = lse - c[0];              // >= 0 always (lse >= max >= c[0])
    const bool  pos = cur.lab > 0;

    // Branchless positive-anchor losses (pred/gt already in registers).
    float sl = 0.f, d, ad;
    d = cur.pd.x - cur.g.x; ad = fabsf(d); sl += (ad < 1.f) ? 0.5f * d * d : ad - 0.5f;
    d = cur.pd.y - cur.g.y; ad = fabsf(d); sl += (ad < 1.f) ? 0.5f * d * d : ad - 0.5f;
    d = cur.pd.z - cur.g.z; ad = fabsf(d); sl += (ad < 1.f) ? 0.5f * d * d : ad - 0.5f;
    d = cur.pd.w - cur.g.w; ad = fabsf(d); sl += (ad < 1.f) ? 0.5f * d * d : ad - 0.5f;
    const float w = pos ? cur.mk : 0.f;
    accm += cur.mk;
    accp += w * (lse - sel);
    accr += w * sl;

    keys[a] = pos ? 0u : (__float_as_uint(bg) | 0x80000000u);  // monotone map; pos -> 0
  }

  // Per-wave reduction; partials to ws (no barrier, no atomics).
  #pragma unroll
  for (int o = 32; o > 0; o >>= 1) {
    accm += __shfl_down(accm, o);
    accp += __shfl_down(accp, o);
    accr += __shfl_down(accr, o);
  }
  if ((tid & 63) == 0) {
    const int gw = b * 4 + (tid >> 6);
    pm[gw] = accm; pp[gw] = accp; pr[gw] = accr;
  }
}

// ---------------------------------------------------------------------------
// k_select: one block (512 threads) per batch row, keys register-resident.
// Exact k-th-largest key via MSB-first search, 2 bits per round (3 candidate
// thresholds, counts monotone) -> 16 barriers. Tie-exact top-k sum.
// ---------------------------------------------------------------------------
#define SEL_T 512
#define RPT   18                               // 8732 = 512*17 + 28

__global__ __launch_bounds__(SEL_T)
void k_select(const uint32_t* __restrict__ keys, double* __restrict__ neg)
{
  __shared__ int    slots[16 * 24 + 8];        // fresh region per round
  __shared__ int    ired[8];
  __shared__ double dred[8];
  const int tid  = threadIdx.x;
  const int w    = tid >> 6;
  const int lane = tid & 63;
  const uint32_t* row = keys + (size_t)blockIdx.x * PRI;

  uint32_t kr[RPT];
  #pragma unroll
  for (int r = 0; r < 17; ++r) kr[r] = row[tid + 512 * r];
  kr[17] = (tid < 28) ? row[tid + 8704] : 0u;  // pad 0: never >= any test (tests >= 2^31)

  // np = zero-key count (pad zeros excluded by tid<28 guard).
  int zc = 0;
  #pragma unroll
  for (int r = 0; r < 17; ++r) zc += (kr[r] == 0u) ? 1 : 0;
  if (tid < 28) zc += (kr[17] == 0u) ? 1 : 0;
  #pragma unroll
  for (int o = 32; o > 0; o >>= 1) zc += __shfl_down(zc, o);
  if (lane == 0) ired[w] = zc;
  __syncthreads();
  int np = 0;
  #pragma unroll
  for (int i = 0; i < 8; ++i) np += ired[i];   // uniform

  int k = np * NPR;
  const int nneg = PRI - np;
  if (k > nneg) k = nneg;

  double result = 0.0;
  if (k > 0) {                                 // uniform branch
    uint32_t cur = 0x80000000u;                // bit31 provably set: nneg >= k
    #pragma unroll 1
    for (int bit = 30; bit >= 1; bit -= 2) {
      const int rnd = (30 - bit) >> 1;
      const uint32_t tA = cur | (3u << (bit - 1));  // bits 11
      const uint32_t tB = cur | (1u << bit);        // bits 10
      const uint32_t tC = cur | (1u << (bit - 1));  // bits 01
      int cA = 0, cB = 0, cC = 0;
      #pragma unroll
      for (int r = 0; r < RPT; ++r) {
        cA += (int)__popcll(__ballot(kr[r] >= tA));
        cB += (int)__popcll(__ballot(kr[r] >= tB));
        cC += (int)__popcll(__ballot(kr[r] >= tC));
      }
      if (lane == 0) {
        int* sl = &slots[rnd * 24];
        sl[w] = cA; sl[8 + w] = cB; sl[16 + w] = cC;
      }
      __syncthreads();
      int TA = 0, TB = 0, TC = 0;
      const int* sl = &slots[rnd * 24];
      #pragma unroll
      for (int i = 0; i < 8; ++i) { TA += sl[i]; TB += sl[8 + i]; TC += sl[16 + i]; }
      cur = (TA >= k) ? tA : (TB >= k) ? tB : (TC >= k) ? tC : cur;  // largest v: count(>=v)>=k
    }
    {                                          // final bit 0
      const uint32_t t = cur | 1u;
      int c = 0;
      #pragma unroll
      for (int r = 0; r < RPT; ++r) c += (int)__popcll(__ballot(kr[r] >= t));
      if (lane == 0) slots[16 * 24 + w] = c;
      __syncthreads();
      int tot = 0;
      #pragma unroll
      for (int i = 0; i < 8; ++i) tot += slots[16 * 24 + i];
      if (tot >= k) cur = t;                   // cur == exact k-th largest key
    }

    const float thr = __uint_as_float(cur & 0x7fffffffu);
    double ssum = 0.0;
    int g = 0;
    #pragma unroll
    for (int r = 0; r < RPT; ++r) {
      if (kr[r] > cur) { ssum += (double)__uint_as_float(kr[r] & 0x7fffffffu); ++g; }
    }
    #pragma unroll
    for (int o = 32; o > 0; o >>= 1) { ssum += __shfl_down(ssum, o); g += __shfl_down(g, o); }
    if (lane == 0) { dred[w] = ssum; ired[w] = g; }
    __syncthreads();
    if (tid == 0) {
      double tot = 0.0; int gg = 0;
      #pragma unroll
      for (int i = 0; i < 8; ++i) { tot += dred[i]; gg += ired[i]; }
      result = tot + (double)(k - gg) * (double)thr;  // tied copies at threshold
    }
  }
  if (tid == 0) neg[blockIdx.x] = result;      // unconditional: ws is poisoned
}

// ---------------------------------------------------------------------------
// k_final: reduce per-wave partials (double accumulation) + write outputs.
// ---------------------------------------------------------------------------
__global__ __launch_bounds__(256)
void k_final(const float* __restrict__ pm, const float* __restrict__ pp,
             const float* __restrict__ pr, const double* __restrict__ neg,
             float* __restrict__ out)
{
  __shared__ double red[4][4];
  const int tid = threadIdx.x, w = tid >> 6, lane = tid & 63;
  double sm = 0.0, sp = 0.0, sr = 0.0, sn = 0.0;
  for (int i = tid; i < NPART; i += 256) {
    sm += (double)pm[i]; sp += (double)pp[i]; sr += (double)pr[i];
  }
  if (tid < BATCH) sn = neg[tid];
  #pragma unroll
  for (int o = 32; o > 0; o >>= 1) {
    sm += __shfl_down(sm, o); sp += __shfl_down(sp, o);
    sr += __shfl_down(sr, o); sn += __shfl_down(sn, o);
  }
  if (lane == 0) { red[0][w] = sm; red[1][w] = sp; red[2][w] = sr; red[3][w] = sn; }
  __syncthreads();
  if (tid == 0) {
    double m = 0, p = 0, r = 0, n = 0;
    #pragma unroll
    for (int i = 0; i < 4; ++i) { m += red[0][i]; p += red[1][i]; r += red[2][i]; n += red[3][i]; }
    out[0] = (float)(r / m);                   // regression_loss / all_batch_pos
    out[1] = (float)((p + n) / m);             // confidence_loss / all_batch_pos
  }
}

extern "C" void kernel_launch(void* const* d_in, const int* in_sizes, int n_in,
                              void* d_out, int out_size, void* d_ws, size_t ws_size,
                              hipStream_t stream) {
  const float* conf   = (const float*)d_in[0];
  const float* pred   = (const float*)d_in[1];
  const int*   labels = (const int*)d_in[2];
  const float* gt     = (const float*)d_in[3];
  const float* mask   = (const float*)d_in[4];
  float* out = (float*)d_out;

  char* ws = (char*)d_ws;
  const size_t keys_bytes = (size_t)TOTAL * sizeof(uint32_t);  // 4,470,784 (8-aligned)
  uint32_t* keys = (uint32_t*)ws;
  float*  pm  = (float*)(ws + keys_bytes);
  float*  pp  = pm + NPART;
  float*  pr  = pp + NPART;
  double* neg = (double*)(ws + keys_bytes + (size_t)3 * NPART * sizeof(float)); // 8-aligned

  k_main<<<GBLK, 256, 0, stream>>>(conf, pred, labels, gt, mask, keys, pm, pp, pr);
  k_select<<<BATCH, SEL_T, 0, stream>>>(keys, neg);
  k_final<<<1, 256, 0, stream>>>(pm, pp, pr, neg, out);
}